// Round 1
// baseline (77.231 us; speedup 1.0000x reference)
//
#include <hip/hip_runtime.h>

#define IN_FLAT 1024
#define BATCH   512
#define NEURONS 4096
#define FOCUS   64
#define BT      16   // batch rows per block (and per xT chunk)

// ---------- helpers ----------
__device__ __forceinline__ unsigned short f32_to_bf16(float f) {
    unsigned int u = __float_as_uint(f);
    // round-to-nearest-even
    unsigned int r = (u + 0x7fffu + ((u >> 16) & 1u)) >> 16;
    return (unsigned short)r;
}

// ---------- kernel 1: transpose + convert ----------
// x [BATCH][IN_FLAT] f32  ->  xt2 chunked bf16: [BATCH/BT][IN_FLAT][BT]
// chunk c holds columns (batches) c*BT .. c*BT+15 of x^T, row-major in i.
__global__ __launch_bounds__(256) void transpose_bf16_kernel(
        const float* __restrict__ x, unsigned short* __restrict__ xt2) {
    __shared__ float tile[32][33];
    const int i0 = blockIdx.x * 32;   // input-feature tile
    const int b0 = blockIdx.y * 32;   // batch tile
    const int t  = threadIdx.x;

    // read phase: 32 rows (batch) x 32 cols (feature), coalesced float4
    {
        const int r  = t >> 3;        // 0..31 batch row
        const int c4 = t & 7;         // 0..7 float4 within row
        float4 v = *reinterpret_cast<const float4*>(
            x + (size_t)(b0 + r) * IN_FLAT + i0 + c4 * 4);
        tile[r][c4 * 4 + 0] = v.x;
        tile[r][c4 * 4 + 1] = v.y;
        tile[r][c4 * 4 + 2] = v.z;
        tile[r][c4 * 4 + 3] = v.w;
    }
    __syncthreads();

    // write phase: each thread emits 4 bf16 (4 consecutive batches of one i row)
    {
        const int il = t >> 3;        // 0..31 feature within tile
        const int q  = t & 7;         // 0..7 -> batches q*4..q*4+3
        ushort4 o;
        o.x = f32_to_bf16(tile[q * 4 + 0][il]);
        o.y = f32_to_bf16(tile[q * 4 + 1][il]);
        o.z = f32_to_bf16(tile[q * 4 + 2][il]);
        o.w = f32_to_bf16(tile[q * 4 + 3][il]);
        // global batch index of first elem: b0 + q*4 ; chunk = (b0+q*4)/BT
        const int chunk  = (b0 >> 4) + (q >> 2);
        const int within = (q & 3) * 4;
        size_t off = (size_t)chunk * IN_FLAT * BT + (size_t)(i0 + il) * BT + within;
        *reinterpret_cast<ushort4*>(xt2 + off) = o;  // 8B store, aligned
    }
}

// ---------- kernel 2: gather-dot ----------
// Each block: 256 neurons x BT batches. LDS holds x^T chunk [1024][16] bf16 = 32KB.
// Lanes span neurons; each thread's per-f "gather" is a contiguous 32B LDS row read.
__global__ __launch_bounds__(256) void gather_dot_kernel(
        const unsigned short* __restrict__ xt2,
        const int*   __restrict__ idx,
        const float* __restrict__ w,
        const float* __restrict__ bias,
        float*       __restrict__ y) {
    __shared__ unsigned short lxt[IN_FLAT * BT];   // [i][bt], 32 KB

    const int nb = blockIdx.x;    // 0..15 neuron tile
    const int bb = blockIdx.y;    // 0..31 batch chunk
    const int t  = threadIdx.x;

    // stage 32KB contiguously: chunk layout matches LDS layout exactly
    {
        const uint4* src = reinterpret_cast<const uint4*>(
            xt2 + (size_t)bb * IN_FLAT * BT);
        uint4* dst = reinterpret_cast<uint4*>(lxt);
        #pragma unroll
        for (int u = 0; u < 8; ++u)
            dst[u * 256 + t] = src[u * 256 + t];
    }
    __syncthreads();

    const int n = nb * 256 + t;
    float acc[BT];
    #pragma unroll
    for (int k = 0; k < BT; ++k) acc[k] = 0.f;

    const int*   ip = idx + (size_t)n * FOCUS;
    const float* wp = w   + (size_t)n * FOCUS;

    #pragma unroll 4
    for (int f4 = 0; f4 < FOCUS / 4; ++f4) {
        const int4   i4 = *reinterpret_cast<const int4*>(ip + f4 * 4);
        const float4 w4 = *reinterpret_cast<const float4*>(wp + f4 * 4);
        const int   iv[4] = {i4.x, i4.y, i4.z, i4.w};
        const float wv[4] = {w4.x, w4.y, w4.z, w4.w};
        #pragma unroll
        for (int j = 0; j < 4; ++j) {
            const int i = iv[j] & (IN_FLAT - 1);
            const float ww = wv[j];
            const uint4* row = reinterpret_cast<const uint4*>(lxt + i * BT);
            const uint4 lo = row[0];
            const uint4 hi = row[1];
            // bf16 pair -> two f32 via shift / mask (no cvt needed)
            acc[0]  += ww * __uint_as_float(lo.x << 16);
            acc[1]  += ww * __uint_as_float(lo.x & 0xffff0000u);
            acc[2]  += ww * __uint_as_float(lo.y << 16);
            acc[3]  += ww * __uint_as_float(lo.y & 0xffff0000u);
            acc[4]  += ww * __uint_as_float(lo.z << 16);
            acc[5]  += ww * __uint_as_float(lo.z & 0xffff0000u);
            acc[6]  += ww * __uint_as_float(lo.w << 16);
            acc[7]  += ww * __uint_as_float(lo.w & 0xffff0000u);
            acc[8]  += ww * __uint_as_float(hi.x << 16);
            acc[9]  += ww * __uint_as_float(hi.x & 0xffff0000u);
            acc[10] += ww * __uint_as_float(hi.y << 16);
            acc[11] += ww * __uint_as_float(hi.y & 0xffff0000u);
            acc[12] += ww * __uint_as_float(hi.z << 16);
            acc[13] += ww * __uint_as_float(hi.z & 0xffff0000u);
            acc[14] += ww * __uint_as_float(hi.w << 16);
            acc[15] += ww * __uint_as_float(hi.w & 0xffff0000u);
        }
    }

    const float bv = bias[n];
    const int b0 = bb * BT;
    #pragma unroll
    for (int k = 0; k < BT; ++k) {
        y[(size_t)(b0 + k) * NEURONS + n] = acc[k] + bv;  // lanes coalesced over n
    }
}

// ---------- launch ----------
extern "C" void kernel_launch(void* const* d_in, const int* in_sizes, int n_in,
                              void* d_out, int out_size, void* d_ws, size_t ws_size,
                              hipStream_t stream) {
    const float* x    = (const float*)d_in[0];
    const int*   idx  = (const int*)  d_in[1];
    const float* w    = (const float*)d_in[2];
    const float* bias = (const float*)d_in[3];
    float*       y    = (float*)d_out;

    // workspace: x^T bf16, batch-chunked: 1024*512*2 = 1 MB
    unsigned short* xt2 = (unsigned short*)d_ws;

    transpose_bf16_kernel<<<dim3(IN_FLAT / 32, BATCH / 32), 256, 0, stream>>>(x, xt2);
    gather_dot_kernel<<<dim3(NEURONS / 256, BATCH / BT), 256, 0, stream>>>(
        xt2, idx, w, bias, y);
}